// Round 16
// baseline (913.036 us; speedup 1.0000x reference)
//
#include <hip/hip_runtime.h>

// ---------------------------------------------------------------------------
// Decoder (GRU, T=50 steps) on MI355X.
// Round 15: tail folded INTO the scan's barrier-wait window.
//   - r12-green base (630us, f32 gx, proven protocol). One structural change:
//     each scan block, between counter publish and poll, computes the
//     non-recurrent half for ITS OWN (quarter, j-slice): h-frags from Hs
//     (valid until post-poll barrier), A-frags streamed from L2-resident
//     Whh_a, output plain-stored to F second half (post-kernel consumer
//     only -> no cross-block race surface). tail_kernel deleted (-25us).
//   - Publish/poll order identical to proven r12; tail work only widens
//     peers' slack.
// Dims: V=10004 E=300 SH=1024 H=512 G=1024 B=128 T=50.
// ---------------------------------------------------------------------------

typedef __bf16 bf16x8 __attribute__((ext_vector_type(8)));
typedef float f32x4 __attribute__((ext_vector_type(4)));
typedef unsigned long long u64;

// ---------------- merged conversion + embedding kernel ---------------------
struct CvtAll {
    const float* src[7];
    int srows[7], scols[7], sstride[7], soff[7], drows[7], dcols[7];
    __bf16* dst[7];
    int blk0[8];
    const int* x; const float* emb; __bf16* embbf;
};

__global__ void cvt_all_kernel(CvtAll p) {
    int bid = blockIdx.x;
    if (bid >= p.blk0[7]) {
        int idx = (bid - p.blk0[7]) * 256 + threadIdx.x;
        if (idx >= 6400 * 320) return;
        int m = idx / 320, c = idx - m * 320;
        int t = m >> 7, b = m & 127;
        int tok = p.x[b * 50 + t];
        float v = (c < 300) ? p.emb[(size_t)tok * 300 + c] : 0.0f;
        p.embbf[idx] = (__bf16)v;
        return;
    }
    int s = 0;
    while (s < 6 && bid >= p.blk0[s + 1]) ++s;
    int idx = (bid - p.blk0[s]) * 256 + threadIdx.x;
    int dc = p.dcols[s];
    int r = idx / dc, c = idx - r * dc;
    if (r >= p.drows[s]) return;
    float v = 0.0f;
    if (r < p.srows[s] && c < p.scols[s])
        v = p.src[s][(size_t)r * p.sstride[s] + p.soff[s] + c];
    p.dst[s][(size_t)r * dc + c] = (__bf16)v;
}

// ---------------- generic bf16 MFMA GEMM: C = A @ B^T ----------------------
struct GemmParams {
    const __bf16* A; int lda;
    const __bf16* B; int ldb; int Brows;
    int K;                      // divisible by 64
    const float* bias;
    float* outF; int ldo; int Nstore;
    __bf16* outBf;
    const __bf16* res;
    const float* add2;
    int ld2; int add2lim;
};

template <int EPI>
__launch_bounds__(256, 2)
__global__ void gemm_bt(GemmParams p) {
    __shared__ __bf16 As[128][72];
    __shared__ __bf16 Bs[128][72];

    const int tid = threadIdx.x;
    const int lane = tid & 63;
    const int wid = tid >> 6;
    const int wr = wid >> 1, wc = wid & 1;
    const int m0 = blockIdx.x * 128, c0 = blockIdx.y * 128;
    const int lrow = lane & 15;
    const int kq = lane >> 4;

    int srow[4], scol[4];
#pragma unroll
    for (int i = 0; i < 4; ++i) {
        int chunk = i * 256 + tid;
        srow[i] = chunk >> 3;
        scol[i] = (chunk & 7) * 8;
    }

    f32x4 acc[4][4];
#pragma unroll
    for (int i = 0; i < 4; ++i)
#pragma unroll
        for (int j = 0; j < 4; ++j) acc[i][j] = (f32x4){0.f, 0.f, 0.f, 0.f};

    const int nkb = p.K >> 6;
    bf16x8 ra[4], rb[4];
#pragma unroll
    for (int i = 0; i < 4; ++i) {
        ra[i] = *reinterpret_cast<const bf16x8*>(
            p.A + (size_t)(m0 + srow[i]) * p.lda + scol[i]);
        bf16x8 z;
#pragma unroll
        for (int q = 0; q < 8; ++q) z[q] = (__bf16)0.0f;
        int grow = c0 + srow[i];
        rb[i] = (grow < p.Brows)
            ? *reinterpret_cast<const bf16x8*>(p.B + (size_t)grow * p.ldb + scol[i])
            : z;
    }

    for (int kb = 0; kb < nkb; ++kb) {
        __syncthreads();
#pragma unroll
        for (int i = 0; i < 4; ++i) {
            *reinterpret_cast<bf16x8*>(&As[srow[i]][scol[i]]) = ra[i];
            *reinterpret_cast<bf16x8*>(&Bs[srow[i]][scol[i]]) = rb[i];
        }
        __syncthreads();

        if (kb + 1 < nkb) {
            int ko = (kb + 1) << 6;
#pragma unroll
            for (int i = 0; i < 4; ++i) {
                ra[i] = *reinterpret_cast<const bf16x8*>(
                    p.A + (size_t)(m0 + srow[i]) * p.lda + ko + scol[i]);
                bf16x8 z;
#pragma unroll
                for (int q = 0; q < 8; ++q) z[q] = (__bf16)0.0f;
                int grow = c0 + srow[i];
                rb[i] = (grow < p.Brows)
                    ? *reinterpret_cast<const bf16x8*>(
                          p.B + (size_t)grow * p.ldb + ko + scol[i])
                    : z;
            }
        }

#pragma unroll
        for (int kk = 0; kk < 2; ++kk) {
            bf16x8 af[4], bfr[4];
#pragma unroll
            for (int m = 0; m < 4; ++m)
                af[m] = *reinterpret_cast<const bf16x8*>(
                    &As[wr * 64 + m * 16 + lrow][kk * 32 + kq * 8]);
#pragma unroll
            for (int n = 0; n < 4; ++n)
                bfr[n] = *reinterpret_cast<const bf16x8*>(
                    &Bs[wc * 64 + n * 16 + lrow][kk * 32 + kq * 8]);
#pragma unroll
            for (int m = 0; m < 4; ++m)
#pragma unroll
                for (int n = 0; n < 4; ++n)
                    acc[m][n] = __builtin_amdgcn_mfma_f32_16x16x32_bf16(
                        af[m], bfr[n], acc[m][n], 0, 0, 0);
        }
    }

#pragma unroll
    for (int m = 0; m < 4; ++m) {
#pragma unroll
        for (int n = 0; n < 4; ++n) {
#pragma unroll
            for (int i = 0; i < 4; ++i) {
                int r = m0 + wr * 64 + m * 16 + kq * 4 + i;
                int c = c0 + wc * 64 + n * 16 + lrow;
                float v = acc[m][n][i];
                if constexpr (EPI == 1) {
                    v = tanhf(v + p.bias[c]);
                    p.outBf[(size_t)r * p.ldo + c] = (__bf16)v;
                    p.outF[(size_t)c * 128 + r] = v;
                } else if constexpr (EPI == 2) {
                    int ro = (r & 127) * 50 + (r >> 7);
                    if (c < 300) {
                        v += p.bias[c] + (float)p.res[(size_t)r * 320 + c];
                        p.outBf[(size_t)ro * 320 + c] = (__bf16)v;
                    } else if (c < 320) {
                        p.outBf[(size_t)ro * 320 + c] = (__bf16)0.0f;
                    }
                } else if constexpr (EPI == 3) {
                    if (c < p.Nstore) p.outF[(size_t)r * p.ldo + c] = v;
                } else {  // EPI == 4
                    if (c < p.Brows) {
                        float v2 = v + p.bias[r];
                        if (p.add2 && r < p.add2lim)
                            v2 += p.add2[(size_t)r * 128 + (c & 127)];
                        p.outF[(size_t)(c >> 7) * p.ldo + (size_t)r * 128 + (c & 127)] = v2;
                    }
                }
            }
        }
    }
}

// ---------------- persistent scan + fused tail -----------------------------
// r12 protocol frozen. Tail for (q, 512+j0 slice) computed in the publish->
// poll window: A-frags streamed from global Whh_a (L2-hot), h-frags from Hs.
#define SCAN_NB 64
__launch_bounds__(256, 1)
__global__ void scan_kernel(const __bf16* __restrict__ Whh_a,   // [3072][512]
                            const float* __restrict__ gxT,      // [50][3072][128]
                            const float* __restrict__ ghcT,     // [3072][128]
                            const float* __restrict__ sesT,     // [512][128] f32
                            u64* __restrict__ F,                // [51][128][256] u64
                            unsigned* __restrict__ cnt) {       // 4 ctr @ stride 32
    __shared__ char smem[131072];
    char* Ws = smem;
    char* Hs = smem + 98304;
    const int tid = threadIdx.x;
    const int lane = tid & 63;
    const int wid = tid >> 6;
    const int wr = wid >> 1, wc = wid & 1;
    const int bid = blockIdx.x;
    const int q = bid >> 4;
    const int j0 = (bid & 15) * 32;
    const int lrow = lane & 15, kq = lane >> 4;

    for (int it = 0; it < 24; ++it) {
        int c = it * 256 + tid;
        int rl = c >> 6, o16 = c & 63;
        int g = rl >> 5, jj = rl & 31;
        bf16x8 v = *reinterpret_cast<const bf16x8*>(
            Whh_a + (size_t)(g * 1024 + j0 + jj) * 512 + o16 * 8);
        *reinterpret_cast<bf16x8*>(Ws + rl * 1024 + ((o16 * 16) ^ ((rl & 7) << 4))) = v;
    }

    const int b_g = q * 32 + wc * 16 + lrow;
    const int jbase  = j0 + wr * 16 + kq * 4;          // scan j (<512)
    const int jbase2 = 512 + j0 + wr * 16 + kq * 4;    // tail j (>=512)

    float cn[4], hprev[4], gcur[12], gpre[12];
    float cn2[4], sv2[4], gcur2[12], gpre2[12];
#pragma unroll
    for (int i = 0; i < 4; ++i) {
        cn[i]  = ghcT[(size_t)(2048 + jbase + i) * 128 + b_g];
        hprev[i] = sesT[(size_t)(jbase + i) * 128 + b_g];
        cn2[i] = ghcT[(size_t)(2048 + jbase2 + i) * 128 + b_g];
        sv2[i] = sesT[(size_t)(jbase2 - 512 + i) * 128 + b_g];
    }
#pragma unroll
    for (int i = 0; i < 4; ++i) {
        gpre[i]      = gxT[(size_t)(jbase + i) * 128 + b_g];
        gpre[4 + i]  = gxT[(size_t)(1024 + jbase + i) * 128 + b_g];
        gpre[8 + i]  = gxT[(size_t)(2048 + jbase + i) * 128 + b_g];
        gpre2[i]     = gxT[(size_t)(jbase2 + i) * 128 + b_g];
        gpre2[4 + i] = gxT[(size_t)(1024 + jbase2 + i) * 128 + b_g];
        gpre2[8 + i] = gxT[(size_t)(2048 + jbase2 + i) * 128 + b_g];
    }

    for (int t = 0; t < 50; ++t) {
        // ---- 1. stage h slice [32 b][512] via agent-scope 8B atomic loads
        for (int it = 0; it < 16; ++it) {
            int c = it * 256 + tid;
            int rl = c >> 7, o8 = c & 127;
            u64 v = __hip_atomic_load(
                F + ((size_t)t * 128 + q * 32 + rl) * 256 + o8,
                __ATOMIC_RELAXED, __HIP_MEMORY_SCOPE_AGENT);
            *reinterpret_cast<u64*>(Hs + rl * 1024 + ((o8 * 8) ^ ((rl & 7) << 4))) = v;
        }
        // ---- 2. rotate gx regs; prefetch t+1 (both roles)
#pragma unroll
        for (int i = 0; i < 12; ++i) { gcur[i] = gpre[i]; gcur2[i] = gpre2[i]; }
        {
            int tn = (t < 49) ? t + 1 : 49;
            const float* gxt = gxT + (size_t)tn * 3072 * 128;
#pragma unroll
            for (int i = 0; i < 4; ++i) {
                gpre[i]      = gxt[(size_t)(jbase + i) * 128 + b_g];
                gpre[4 + i]  = gxt[(size_t)(1024 + jbase + i) * 128 + b_g];
                gpre[8 + i]  = gxt[(size_t)(2048 + jbase + i) * 128 + b_g];
                gpre2[i]     = gxt[(size_t)(jbase2 + i) * 128 + b_g];
                gpre2[4 + i] = gxt[(size_t)(1024 + jbase2 + i) * 128 + b_g];
                gpre2[8 + i] = gxt[(size_t)(2048 + jbase2 + i) * 128 + b_g];
            }
        }
        // ---- 3. lgkm-only barrier (Hs visible; vmem loads stay in flight)
        asm volatile("s_waitcnt lgkmcnt(0)\n\ts_barrier" ::: "memory");
        __builtin_amdgcn_sched_barrier(0);

        // ---- 4. scan MFMA over K=512 (Ws in LDS)
        f32x4 acc[3];
#pragma unroll
        for (int g = 0; g < 3; ++g) acc[g] = (f32x4){0.f, 0.f, 0.f, 0.f};
        const int hrow = wc * 16 + lrow;
        const int arow0 = wr * 16 + lrow;
        for (int kb = 0; kb < 16; ++kb) {
            int ko = kb * 64 + kq * 16;
            bf16x8 hfrag = *reinterpret_cast<const bf16x8*>(
                Hs + hrow * 1024 + (ko ^ ((hrow & 7) << 4)));
#pragma unroll
            for (int g = 0; g < 3; ++g) {
                int arow = g * 32 + arow0;
                bf16x8 wfrag = *reinterpret_cast<const bf16x8*>(
                    Ws + arow * 1024 + (ko ^ ((arow & 7) << 4)));
                acc[g] = __builtin_amdgcn_mfma_f32_16x16x32_bf16(
                    wfrag, hfrag, acc[g], 0, 0, 0);
            }
        }

        // ---- 5. scan gates + h store (agent atomic)
        union { u64 u; __bf16 h[4]; } pk;
#pragma unroll
        for (int i = 0; i < 4; ++i) {
            float r = 1.0f / (1.0f + expf(-(gcur[i] + acc[0][i])));
            float z = 1.0f / (1.0f + expf(-(gcur[4 + i] + acc[1][i])));
            float nn = tanhf(gcur[8 + i] + r * (acc[2][i] + cn[i]));
            float hn = (1.0f - z) * nn + z * hprev[i];
            hprev[i] = hn;
            pk.h[i] = (__bf16)hn;
        }
        __hip_atomic_store(
            F + ((size_t)(t + 1) * 128 + b_g) * 256 + (jbase >> 2), pk.u,
            __ATOMIC_RELAXED, __HIP_MEMORY_SCOPE_AGENT);

        // ---- 6. drain + publish (proven order), then tail fills the window
        if (t < 49) {
            __syncthreads();               // all waves' h-stores drained
            if (tid == 0)
                __hip_atomic_fetch_add(cnt + q * 32, 1u,
                                       __ATOMIC_RELAXED, __HIP_MEMORY_SCOPE_AGENT);
        }

        // ---- 7. fused tail: j in [512+j0, 512+j0+32), A streamed from L2
        {
            f32x4 acc2[3];
#pragma unroll
            for (int g = 0; g < 3; ++g) acc2[g] = (f32x4){0.f, 0.f, 0.f, 0.f};
            for (int kb = 0; kb < 16; ++kb) {
                int ko = kb * 64 + kq * 16;
                bf16x8 hfrag = *reinterpret_cast<const bf16x8*>(
                    Hs + hrow * 1024 + (ko ^ ((hrow & 7) << 4)));
#pragma unroll
                for (int g = 0; g < 3; ++g) {
                    bf16x8 af2 = *reinterpret_cast<const bf16x8*>(
                        Whh_a + (size_t)(g * 1024 + 512 + j0 + wr * 16 + lrow) * 512
                              + kb * 32 + kq * 8);
                    acc2[g] = __builtin_amdgcn_mfma_f32_16x16x32_bf16(
                        af2, hfrag, acc2[g], 0, 0, 0);
                }
            }
            union { u64 u; __bf16 h[4]; } pk2;
#pragma unroll
            for (int i = 0; i < 4; ++i) {
                float r = 1.0f / (1.0f + expf(-(gcur2[i] + acc2[0][i])));
                float z = 1.0f / (1.0f + expf(-(gcur2[4 + i] + acc2[1][i])));
                float nn = tanhf(gcur2[8 + i] + r * (acc2[2][i] + cn2[i]));
                pk2.h[i] = (__bf16)((1.0f - z) * nn + z * sv2[i]);
            }
            // plain store to F second half; consumed only post-kernel (o-GEMM)
            F[((size_t)(t + 1) * 128 + b_g) * 256 + 128 + ((jbase2 - 512) >> 2)] = pk2.u;
        }

        // ---- 8. poll peers + step barrier (proven)
        if (t < 49) {
            if (tid == 0) {
                unsigned tgt = (unsigned)(t + 1) * 16u;
                while (__hip_atomic_load(cnt + q * 32, __ATOMIC_RELAXED,
                                         __HIP_MEMORY_SCOPE_AGENT) < tgt)
                    __builtin_amdgcn_s_sleep(1);
            }
            __syncthreads();
        }
    }
}

// ---------------------------------------------------------------------------
extern "C" void kernel_launch(void* const* d_in, const int* in_sizes, int n_in,
                              void* d_out, int out_size, void* d_ws, size_t ws_size,
                              hipStream_t stream) {
    const float* ses_enc = (const float*)d_in[0];
    const int*   x       = (const int*)d_in[1];
    const float* emb     = (const float*)d_in[2];
    const float* Wih     = (const float*)d_in[3];
    const float* Whh     = (const float*)d_in[4];
    const float* bih     = (const float*)d_in[5];
    const float* bhh     = (const float*)d_in[6];
    const float* W1      = (const float*)d_in[7];
    const float* b1      = (const float*)d_in[8];
    const float* W2      = (const float*)d_in[9];
    const float* b2      = (const float*)d_in[10];
    const float* Wout    = (const float*)d_in[11];
    float* out = (float*)d_out;

    char* ws = (char*)d_ws;
    float*  sesT      = (float*)(ws + 0);
    float*  ghcT      = (float*)(ws + 262144);
    __bf16* o_bf      = (__bf16*)(ws + 1835008);
    __bf16* W1_bf     = (__bf16*)(ws + 5931008);
    __bf16* Whh_a_bf  = (__bf16*)(ws + 6979584);
    __bf16* Whh_b_bf  = (__bf16*)(ws + 10125312);
    __bf16* Wih_bf    = (__bf16*)(ws + 13271040);
    __bf16* W2_bf     = (__bf16*)(ws + 15237120);
    __bf16* Wout_bf   = (__bf16*)(ws + 15851520);
    __bf16* sesenc_bf = (__bf16*)(ws + 22323200);
    unsigned* cnt     = (unsigned*)(ws + 22585344);

    char* ob = (char*)d_out;
    float*  gxT     = (float*)ob;                  // f32 again (r12 layout)
    __bf16* emb_bf  = (__bf16*)(ob + 80000000);
    __bf16* F       = (__bf16*)(ob + 88000000);

    dim3 blk(256);

    CvtAll ca;
    const float* csrc[7]  = {W1, Whh, Whh, Wih, W2, Wout, ses_enc};
    int csr[7]  = {512, 3072, 3072, 3072, 300, 10004, 128};
    int csc[7]  = {1024, 512, 512, 300, 1024, 300, 1024};
    int cst[7]  = {1024, 1024, 1024, 300, 1024, 300, 1024};
    int cso[7]  = {0, 0, 512, 0, 0, 0, 0};
    __bf16* cdst[7] = {W1_bf, Whh_a_bf, Whh_b_bf, Wih_bf, W2_bf, Wout_bf, sesenc_bf};
    int cdr[7]  = {512, 3072, 3072, 3072, 300, 10112, 128};
    int cdc[7]  = {1024, 512, 512, 320, 1024, 320, 1024};
    int b0 = 0;
    for (int s = 0; s < 7; ++s) {
        ca.src[s] = csrc[s]; ca.srows[s] = csr[s]; ca.scols[s] = csc[s];
        ca.sstride[s] = cst[s]; ca.soff[s] = cso[s];
        ca.dst[s] = cdst[s]; ca.drows[s] = cdr[s]; ca.dcols[s] = cdc[s];
        ca.blk0[s] = b0;
        b0 += (cdr[s] * cdc[s] + 255) / 256;
    }
    ca.blk0[7] = b0;
    ca.x = x; ca.emb = emb; ca.embbf = emb_bf;
    int total_blocks = b0 + (6400 * 320) / 256;
    cvt_all_kernel<<<total_blocks, 256, 0, stream>>>(ca);
    hipMemsetAsync(cnt, 0, 1024, stream);

    GemmParams P;

    // ses = tanh(ses_enc @ W1^T + b1) -> F[0][b][0:512] bf16 + sesT [512][b] f32
    P = {sesenc_bf, 1024, W1_bf, 1024, 512, 1024, b1, sesT, 1024, 512, F,
         nullptr, nullptr, 0, 0};
    gemm_bt<1><<<dim3(1, 4), blk, 0, stream>>>(P);

    // ghcT[c][b] = (Whh[:,512:] @ ses^T) + bhh
    P = {Whh_b_bf, 512, F, 1024, 128, 512, bhh, ghcT, 0, 0, nullptr,
         nullptr, nullptr, 0, 0};
    gemm_bt<4><<<dim3(24, 1), blk, 0, stream>>>(P);

    // gxT[t][c][b] = (Wih @ emb^T) + bih (+ ghcT for c<2048)
    P = {Wih_bf, 320, emb_bf, 320, 6400, 320, bih, gxT, 3072 * 128, 0, nullptr,
         nullptr, ghcT, 0, 2048};
    gemm_bt<4><<<dim3(24, 50), blk, 0, stream>>>(P);

    // ---- persistent scan + fused tail (single kernel) ----
    scan_kernel<<<SCAN_NB, 256, 0, stream>>>(
        Whh_a_bf, gxT, ghcT, sesT, (u64*)F, cnt);

    // o = hnew @ W2^T + b2 + emb  -> bf16, rows remapped (t,b)->(b,t)
    P = {F + 128 * 1024, 1024, W2_bf, 1024, 300, 1024, b2, nullptr, 0, 300, o_bf,
         emb_bf, nullptr, 0, 0};
    gemm_bt<2><<<dim3(50, 3), blk, 0, stream>>>(P);

    // logits = o @ Wout^T -> d_out f32 (overwrites all scratch regions)
    P = {o_bf, 320, Wout_bf, 320, 10112, 320, nullptr, out, 10004, 10004, nullptr,
         nullptr, nullptr, 0, 0};
    gemm_bt<3><<<dim3(50, 79), blk, 0, stream>>>(P);

    (void)in_sizes; (void)n_in; (void)out_size; (void)ws_size;
}

// Round 17
// 647.496 us; speedup vs baseline: 1.4101x; 1.4101x over previous
//
#include <hip/hip_runtime.h>

// ---------------------------------------------------------------------------
// Decoder (GRU, T=50 steps) on MI355X.
// Round 16: r12-green base (630us) + double-buffered GEMM LDS.
//   - gemm_bt: As[2]/Bs[2] (73.7KB, 2 blocks/CU kept) -> ONE barrier per
//     K-tile (was 2). Schedule: write buf[kb&1] | sync | issue kb+1 loads |
//     MFMA buf[kb&1]. Block-local change only; epilogues identical.
//   - Scan FROZEN at r12 protocol (342us; r13/r15 variants regressed).
//   - Tail separate kernel (r15 fusion regressed: uncoalesced A-stream).
// Dims: V=10004 E=300 SH=1024 H=512 G=1024 B=128 T=50.
// ---------------------------------------------------------------------------

typedef __bf16 bf16x8 __attribute__((ext_vector_type(8)));
typedef float f32x4 __attribute__((ext_vector_type(4)));
typedef unsigned long long u64;

// ---------------- merged conversion + embedding kernel ---------------------
struct CvtAll {
    const float* src[7];
    int srows[7], scols[7], sstride[7], soff[7], drows[7], dcols[7];
    __bf16* dst[7];
    int blk0[8];
    const int* x; const float* emb; __bf16* embbf;
};

__global__ void cvt_all_kernel(CvtAll p) {
    int bid = blockIdx.x;
    if (bid >= p.blk0[7]) {
        int idx = (bid - p.blk0[7]) * 256 + threadIdx.x;
        if (idx >= 6400 * 320) return;
        int m = idx / 320, c = idx - m * 320;
        int t = m >> 7, b = m & 127;
        int tok = p.x[b * 50 + t];
        float v = (c < 300) ? p.emb[(size_t)tok * 300 + c] : 0.0f;
        p.embbf[idx] = (__bf16)v;
        return;
    }
    int s = 0;
    while (s < 6 && bid >= p.blk0[s + 1]) ++s;
    int idx = (bid - p.blk0[s]) * 256 + threadIdx.x;
    int dc = p.dcols[s];
    int r = idx / dc, c = idx - r * dc;
    if (r >= p.drows[s]) return;
    float v = 0.0f;
    if (r < p.srows[s] && c < p.scols[s])
        v = p.src[s][(size_t)r * p.sstride[s] + p.soff[s] + c];
    p.dst[s][(size_t)r * dc + c] = (__bf16)v;
}

// ---------------- generic bf16 MFMA GEMM: C = A @ B^T ----------------------
// BK=64, DOUBLE-BUFFERED LDS: one barrier per K-tile.
struct GemmParams {
    const __bf16* A; int lda;
    const __bf16* B; int ldb; int Brows;
    int K;                      // divisible by 64
    const float* bias;
    float* outF; int ldo; int Nstore;
    __bf16* outBf;
    const __bf16* res;
    const float* add2;
    int ld2; int add2lim;
};

template <int EPI>
__launch_bounds__(256, 2)
__global__ void gemm_bt(GemmParams p) {
    __shared__ __bf16 As[2][128][72];
    __shared__ __bf16 Bs[2][128][72];

    const int tid = threadIdx.x;
    const int lane = tid & 63;
    const int wid = tid >> 6;
    const int wr = wid >> 1, wc = wid & 1;
    const int m0 = blockIdx.x * 128, c0 = blockIdx.y * 128;
    const int lrow = lane & 15;
    const int kq = lane >> 4;

    int srow[4], scol[4];
#pragma unroll
    for (int i = 0; i < 4; ++i) {
        int chunk = i * 256 + tid;
        srow[i] = chunk >> 3;
        scol[i] = (chunk & 7) * 8;
    }

    f32x4 acc[4][4];
#pragma unroll
    for (int i = 0; i < 4; ++i)
#pragma unroll
        for (int j = 0; j < 4; ++j) acc[i][j] = (f32x4){0.f, 0.f, 0.f, 0.f};

    const int nkb = p.K >> 6;
    bf16x8 ra[4], rb[4];
    // ---- prologue: tile 0 into regs ----
#pragma unroll
    for (int i = 0; i < 4; ++i) {
        ra[i] = *reinterpret_cast<const bf16x8*>(
            p.A + (size_t)(m0 + srow[i]) * p.lda + scol[i]);
        bf16x8 z;
#pragma unroll
        for (int q = 0; q < 8; ++q) z[q] = (__bf16)0.0f;
        int grow = c0 + srow[i];
        rb[i] = (grow < p.Brows)
            ? *reinterpret_cast<const bf16x8*>(p.B + (size_t)grow * p.ldb + scol[i])
            : z;
    }

    for (int kb = 0; kb < nkb; ++kb) {
        const int cur = kb & 1;
        // ---- write tile kb into buf[cur] (last read of buf[cur] completed
        //      before the barrier of iteration kb-1 -> WAR-safe)
#pragma unroll
        for (int i = 0; i < 4; ++i) {
            *reinterpret_cast<bf16x8*>(&As[cur][srow[i]][scol[i]]) = ra[i];
            *reinterpret_cast<bf16x8*>(&Bs[cur][srow[i]][scol[i]]) = rb[i];
        }
        __syncthreads();               // tile kb visible (single barrier/iter)

        // ---- issue tile kb+1 loads; land during MFMA ----
        if (kb + 1 < nkb) {
            int ko = (kb + 1) << 6;
#pragma unroll
            for (int i = 0; i < 4; ++i) {
                ra[i] = *reinterpret_cast<const bf16x8*>(
                    p.A + (size_t)(m0 + srow[i]) * p.lda + ko + scol[i]);
                bf16x8 z;
#pragma unroll
                for (int q = 0; q < 8; ++q) z[q] = (__bf16)0.0f;
                int grow = c0 + srow[i];
                rb[i] = (grow < p.Brows)
                    ? *reinterpret_cast<const bf16x8*>(
                          p.B + (size_t)grow * p.ldb + ko + scol[i])
                    : z;
            }
        }

        // ---- MFMA over the two K=32 halves of tile kb ----
#pragma unroll
        for (int kk = 0; kk < 2; ++kk) {
            bf16x8 af[4], bfr[4];
#pragma unroll
            for (int m = 0; m < 4; ++m)
                af[m] = *reinterpret_cast<const bf16x8*>(
                    &As[cur][wr * 64 + m * 16 + lrow][kk * 32 + kq * 8]);
#pragma unroll
            for (int n = 0; n < 4; ++n)
                bfr[n] = *reinterpret_cast<const bf16x8*>(
                    &Bs[cur][wc * 64 + n * 16 + lrow][kk * 32 + kq * 8]);
#pragma unroll
            for (int m = 0; m < 4; ++m)
#pragma unroll
                for (int n = 0; n < 4; ++n)
                    acc[m][n] = __builtin_amdgcn_mfma_f32_16x16x32_bf16(
                        af[m], bfr[n], acc[m][n], 0, 0, 0);
        }
    }

#pragma unroll
    for (int m = 0; m < 4; ++m) {
#pragma unroll
        for (int n = 0; n < 4; ++n) {
#pragma unroll
            for (int i = 0; i < 4; ++i) {
                int r = m0 + wr * 64 + m * 16 + kq * 4 + i;
                int c = c0 + wc * 64 + n * 16 + lrow;
                float v = acc[m][n][i];
                if constexpr (EPI == 1) {
                    v = tanhf(v + p.bias[c]);
                    p.outBf[(size_t)r * p.ldo + c] = (__bf16)v;
                    p.outF[(size_t)c * 128 + r] = v;
                } else if constexpr (EPI == 2) {
                    int ro = (r & 127) * 50 + (r >> 7);
                    if (c < 300) {
                        v += p.bias[c] + (float)p.res[(size_t)r * 320 + c];
                        p.outBf[(size_t)ro * 320 + c] = (__bf16)v;
                    } else if (c < 320) {
                        p.outBf[(size_t)ro * 320 + c] = (__bf16)0.0f;
                    }
                } else if constexpr (EPI == 3) {
                    if (c < p.Nstore) p.outF[(size_t)r * p.ldo + c] = v;
                } else {  // EPI == 4
                    if (c < p.Brows) {
                        float v2 = v + p.bias[r];
                        if (p.add2 && r < p.add2lim)
                            v2 += p.add2[(size_t)r * 128 + (c & 127)];
                        p.outF[(size_t)(c >> 7) * p.ldo + (size_t)r * 128 + (c & 127)] = v2;
                    }
                }
            }
        }
    }
}

// ---------------- persistent scan (r12 protocol, FROZEN) -------------------
#define SCAN_NB 64
__launch_bounds__(256, 1)
__global__ void scan_kernel(const __bf16* __restrict__ Whh_a,   // [3072][512]
                            const float* __restrict__ gxT,      // [50][3072][128]
                            const float* __restrict__ ghcT,     // [3072][128]
                            const float* __restrict__ sesT,     // [512][128] f32
                            u64* __restrict__ F,                // [51][128][256] u64
                            unsigned* __restrict__ cnt) {       // 4 ctr @ stride 32
    __shared__ char smem[131072];
    char* Ws = smem;
    char* Hs = smem + 98304;
    const int tid = threadIdx.x;
    const int lane = tid & 63;
    const int wid = tid >> 6;
    const int wr = wid >> 1, wc = wid & 1;
    const int bid = blockIdx.x;
    const int q = bid >> 4;
    const int j0 = (bid & 15) * 32;
    const int lrow = lane & 15, kq = lane >> 4;

    for (int it = 0; it < 24; ++it) {
        int c = it * 256 + tid;
        int rl = c >> 6, o16 = c & 63;
        int g = rl >> 5, jj = rl & 31;
        bf16x8 v = *reinterpret_cast<const bf16x8*>(
            Whh_a + (size_t)(g * 1024 + j0 + jj) * 512 + o16 * 8);
        *reinterpret_cast<bf16x8*>(Ws + rl * 1024 + ((o16 * 16) ^ ((rl & 7) << 4))) = v;
    }

    const int b_g = q * 32 + wc * 16 + lrow;
    const int jbase = j0 + wr * 16 + kq * 4;

    float cn[4], hprev[4], gcur[12], gpre[12];
#pragma unroll
    for (int i = 0; i < 4; ++i) {
        cn[i] = ghcT[(size_t)(2048 + jbase + i) * 128 + b_g];
        hprev[i] = sesT[(size_t)(jbase + i) * 128 + b_g];
    }
#pragma unroll
    for (int i = 0; i < 4; ++i) {
        gpre[i]     = gxT[(size_t)(jbase + i) * 128 + b_g];
        gpre[4 + i] = gxT[(size_t)(1024 + jbase + i) * 128 + b_g];
        gpre[8 + i] = gxT[(size_t)(2048 + jbase + i) * 128 + b_g];
    }

    for (int t = 0; t < 50; ++t) {
        for (int it = 0; it < 16; ++it) {
            int c = it * 256 + tid;
            int rl = c >> 7, o8 = c & 127;
            u64 v = __hip_atomic_load(
                F + ((size_t)t * 128 + q * 32 + rl) * 256 + o8,
                __ATOMIC_RELAXED, __HIP_MEMORY_SCOPE_AGENT);
            *reinterpret_cast<u64*>(Hs + rl * 1024 + ((o8 * 8) ^ ((rl & 7) << 4))) = v;
        }
#pragma unroll
        for (int i = 0; i < 12; ++i) gcur[i] = gpre[i];
        {
            int tn = (t < 49) ? t + 1 : 49;
            const float* gxt = gxT + (size_t)tn * 3072 * 128;
#pragma unroll
            for (int i = 0; i < 4; ++i) {
                gpre[i]     = gxt[(size_t)(jbase + i) * 128 + b_g];
                gpre[4 + i] = gxt[(size_t)(1024 + jbase + i) * 128 + b_g];
                gpre[8 + i] = gxt[(size_t)(2048 + jbase + i) * 128 + b_g];
            }
        }
        asm volatile("s_waitcnt lgkmcnt(0)\n\ts_barrier" ::: "memory");
        __builtin_amdgcn_sched_barrier(0);

        f32x4 acc[3];
#pragma unroll
        for (int g = 0; g < 3; ++g) acc[g] = (f32x4){0.f, 0.f, 0.f, 0.f};
        const int hrow = wc * 16 + lrow;
        const int arow0 = wr * 16 + lrow;
        for (int kb = 0; kb < 16; ++kb) {
            int ko = kb * 64 + kq * 16;
            bf16x8 hfrag = *reinterpret_cast<const bf16x8*>(
                Hs + hrow * 1024 + (ko ^ ((hrow & 7) << 4)));
#pragma unroll
            for (int g = 0; g < 3; ++g) {
                int arow = g * 32 + arow0;
                bf16x8 wfrag = *reinterpret_cast<const bf16x8*>(
                    Ws + arow * 1024 + (ko ^ ((arow & 7) << 4)));
                acc[g] = __builtin_amdgcn_mfma_f32_16x16x32_bf16(
                    wfrag, hfrag, acc[g], 0, 0, 0);
            }
        }

        union { u64 u; __bf16 h[4]; } pk;
#pragma unroll
        for (int i = 0; i < 4; ++i) {
            float r = 1.0f / (1.0f + expf(-(gcur[i] + acc[0][i])));
            float z = 1.0f / (1.0f + expf(-(gcur[4 + i] + acc[1][i])));
            float nn = tanhf(gcur[8 + i] + r * (acc[2][i] + cn[i]));
            float hn = (1.0f - z) * nn + z * hprev[i];
            hprev[i] = hn;
            pk.h[i] = (__bf16)hn;
        }
        __hip_atomic_store(
            F + ((size_t)(t + 1) * 128 + b_g) * 256 + (jbase >> 2), pk.u,
            __ATOMIC_RELAXED, __HIP_MEMORY_SCOPE_AGENT);

        if (t < 49) {
            __syncthreads();
            if (tid == 0) {
                __hip_atomic_fetch_add(cnt + q * 32, 1u,
                                       __ATOMIC_RELAXED, __HIP_MEMORY_SCOPE_AGENT);
                unsigned tgt = (unsigned)(t + 1) * 16u;
                while (__hip_atomic_load(cnt + q * 32, __ATOMIC_RELAXED,
                                         __HIP_MEMORY_SCOPE_AGENT) < tgt)
                    __builtin_amdgcn_s_sleep(1);
            }
            __syncthreads();
        }
    }
}

// ---------------- deferred non-recurrent half (j in [512,1024)) ------------
__launch_bounds__(256, 1)
__global__ void tail_kernel(const __bf16* __restrict__ Whh_a,
                            const float* __restrict__ gxT,
                            const float* __restrict__ ghcT,
                            const float* __restrict__ sesT,
                            __bf16* __restrict__ F) {
    __shared__ char smem[131072];
    char* Ws = smem;
    char* Hs = smem + 98304;
    const int tid = threadIdx.x;
    const int lane = tid & 63;
    const int wid = tid >> 6;
    const int wr = wid >> 1, wc = wid & 1;
    const int bid = blockIdx.x;
    const int tseg = bid >> 6;
    const int rem = bid & 63;
    const int q = rem >> 4;
    const int j0 = 512 + (rem & 15) * 32;
    const int lrow = lane & 15, kq = lane >> 4;

    const int t0 = (tseg < 2) ? tseg * 13 : 26 + (tseg - 2) * 12;
    const int t1 = (tseg < 2) ? t0 + 13 : t0 + 12;

    for (int it = 0; it < 24; ++it) {
        int c = it * 256 + tid;
        int rl = c >> 6, o16 = c & 63;
        int g = rl >> 5, jj = rl & 31;
        bf16x8 v = *reinterpret_cast<const bf16x8*>(
            Whh_a + (size_t)(g * 1024 + j0 + jj) * 512 + o16 * 8);
        *reinterpret_cast<bf16x8*>(Ws + rl * 1024 + ((o16 * 16) ^ ((rl & 7) << 4))) = v;
    }

    const int b_g = q * 32 + wc * 16 + lrow;
    const int jbase = j0 + wr * 16 + kq * 4;

    float cn[4], sv[4];
#pragma unroll
    for (int i = 0; i < 4; ++i) {
        cn[i] = ghcT[(size_t)(2048 + jbase + i) * 128 + b_g];
        sv[i] = sesT[(size_t)(jbase + i - 512) * 128 + b_g];
    }

    for (int tt = t0; tt < t1; ++tt) {
        for (int it = 0; it < 8; ++it) {
            int c = it * 256 + tid;
            int rl = c >> 6, o16 = c & 63;
            bf16x8 v = *reinterpret_cast<const bf16x8*>(
                F + ((size_t)tt * 128 + q * 32 + rl) * 1024 + o16 * 8);
            *reinterpret_cast<bf16x8*>(Hs + rl * 1024 + ((o16 * 16) ^ ((rl & 7) << 4))) = v;
        }
        const float* gxt = gxT + (size_t)tt * 3072 * 128;
        float g0[12];
#pragma unroll
        for (int i = 0; i < 4; ++i) {
            g0[i]     = gxt[(size_t)(jbase + i) * 128 + b_g];
            g0[4 + i] = gxt[(size_t)(1024 + jbase + i) * 128 + b_g];
            g0[8 + i] = gxt[(size_t)(2048 + jbase + i) * 128 + b_g];
        }
        __syncthreads();

        f32x4 acc[3];
#pragma unroll
        for (int g = 0; g < 3; ++g) acc[g] = (f32x4){0.f, 0.f, 0.f, 0.f};
        const int hrow = wc * 16 + lrow;
        const int arow0 = wr * 16 + lrow;
        for (int kb = 0; kb < 16; ++kb) {
            int ko = kb * 64 + kq * 16;
            bf16x8 hfrag = *reinterpret_cast<const bf16x8*>(
                Hs + hrow * 1024 + (ko ^ ((hrow & 7) << 4)));
#pragma unroll
            for (int g = 0; g < 3; ++g) {
                int arow = g * 32 + arow0;
                bf16x8 wfrag = *reinterpret_cast<const bf16x8*>(
                    Ws + arow * 1024 + (ko ^ ((arow & 7) << 4)));
                acc[g] = __builtin_amdgcn_mfma_f32_16x16x32_bf16(
                    wfrag, hfrag, acc[g], 0, 0, 0);
            }
        }

        union { u64 u; __bf16 h[4]; } pk;
#pragma unroll
        for (int i = 0; i < 4; ++i) {
            float r = 1.0f / (1.0f + expf(-(g0[i] + acc[0][i])));
            float z = 1.0f / (1.0f + expf(-(g0[4 + i] + acc[1][i])));
            float nn = tanhf(g0[8 + i] + r * (acc[2][i] + cn[i]));
            pk.h[i] = (__bf16)((1.0f - z) * nn + z * sv[i]);
        }
        *reinterpret_cast<u64*>(F + ((size_t)(tt + 1) * 128 + b_g) * 1024 + jbase) = pk.u;
        __syncthreads();
    }
}

// ---------------------------------------------------------------------------
extern "C" void kernel_launch(void* const* d_in, const int* in_sizes, int n_in,
                              void* d_out, int out_size, void* d_ws, size_t ws_size,
                              hipStream_t stream) {
    const float* ses_enc = (const float*)d_in[0];
    const int*   x       = (const int*)d_in[1];
    const float* emb     = (const float*)d_in[2];
    const float* Wih     = (const float*)d_in[3];
    const float* Whh     = (const float*)d_in[4];
    const float* bih     = (const float*)d_in[5];
    const float* bhh     = (const float*)d_in[6];
    const float* W1      = (const float*)d_in[7];
    const float* b1      = (const float*)d_in[8];
    const float* W2      = (const float*)d_in[9];
    const float* b2      = (const float*)d_in[10];
    const float* Wout    = (const float*)d_in[11];
    float* out = (float*)d_out;

    char* ws = (char*)d_ws;
    float*  sesT      = (float*)(ws + 0);
    float*  ghcT      = (float*)(ws + 262144);
    __bf16* o_bf      = (__bf16*)(ws + 1835008);
    __bf16* W1_bf     = (__bf16*)(ws + 5931008);
    __bf16* Whh_a_bf  = (__bf16*)(ws + 6979584);
    __bf16* Whh_b_bf  = (__bf16*)(ws + 10125312);
    __bf16* Wih_bf    = (__bf16*)(ws + 13271040);
    __bf16* W2_bf     = (__bf16*)(ws + 15237120);
    __bf16* Wout_bf   = (__bf16*)(ws + 15851520);
    __bf16* sesenc_bf = (__bf16*)(ws + 22323200);
    unsigned* cnt     = (unsigned*)(ws + 22585344);

    char* ob = (char*)d_out;
    float*  gxT     = (float*)ob;
    __bf16* emb_bf  = (__bf16*)(ob + 80000000);
    __bf16* F       = (__bf16*)(ob + 88000000);

    dim3 blk(256);

    CvtAll ca;
    const float* csrc[7]  = {W1, Whh, Whh, Wih, W2, Wout, ses_enc};
    int csr[7]  = {512, 3072, 3072, 3072, 300, 10004, 128};
    int csc[7]  = {1024, 512, 512, 300, 1024, 300, 1024};
    int cst[7]  = {1024, 1024, 1024, 300, 1024, 300, 1024};
    int cso[7]  = {0, 0, 512, 0, 0, 0, 0};
    __bf16* cdst[7] = {W1_bf, Whh_a_bf, Whh_b_bf, Wih_bf, W2_bf, Wout_bf, sesenc_bf};
    int cdr[7]  = {512, 3072, 3072, 3072, 300, 10112, 128};
    int cdc[7]  = {1024, 512, 512, 320, 1024, 320, 1024};
    int b0 = 0;
    for (int s = 0; s < 7; ++s) {
        ca.src[s] = csrc[s]; ca.srows[s] = csr[s]; ca.scols[s] = csc[s];
        ca.sstride[s] = cst[s]; ca.soff[s] = cso[s];
        ca.dst[s] = cdst[s]; ca.drows[s] = cdr[s]; ca.dcols[s] = cdc[s];
        ca.blk0[s] = b0;
        b0 += (cdr[s] * cdc[s] + 255) / 256;
    }
    ca.blk0[7] = b0;
    ca.x = x; ca.emb = emb; ca.embbf = emb_bf;
    int total_blocks = b0 + (6400 * 320) / 256;
    cvt_all_kernel<<<total_blocks, 256, 0, stream>>>(ca);
    hipMemsetAsync(cnt, 0, 1024, stream);

    GemmParams P;

    // ses = tanh(ses_enc @ W1^T + b1) -> F[0][b][0:512] bf16 + sesT [512][b] f32
    P = {sesenc_bf, 1024, W1_bf, 1024, 512, 1024, b1, sesT, 1024, 512, F,
         nullptr, nullptr, 0, 0};
    gemm_bt<1><<<dim3(1, 4), blk, 0, stream>>>(P);

    // ghcT[c][b] = (Whh[:,512:] @ ses^T) + bhh
    P = {Whh_b_bf, 512, F, 1024, 128, 512, bhh, ghcT, 0, 0, nullptr,
         nullptr, nullptr, 0, 0};
    gemm_bt<4><<<dim3(24, 1), blk, 0, stream>>>(P);

    // gxT[t][c][b] = (Wih @ emb^T) + bih (+ ghcT for c<2048)
    P = {Wih_bf, 320, emb_bf, 320, 6400, 320, bih, gxT, 3072 * 128, 0, nullptr,
         nullptr, ghcT, 0, 2048};
    gemm_bt<4><<<dim3(24, 50), blk, 0, stream>>>(P);

    // ---- persistent scan (recurrent half) ----
    scan_kernel<<<SCAN_NB, 256, 0, stream>>>(
        Whh_a_bf, gxT, ghcT, sesT, (u64*)F, cnt);

    // ---- deferred non-recurrent half ----
    tail_kernel<<<256, 256, 0, stream>>>(Whh_a_bf, gxT, ghcT, sesT, F);

    // o = hnew @ W2^T + b2 + emb  -> bf16, rows remapped (t,b)->(b,t)
    P = {F + 128 * 1024, 1024, W2_bf, 1024, 300, 1024, b2, nullptr, 0, 300, o_bf,
         emb_bf, nullptr, 0, 0};
    gemm_bt<2><<<dim3(50, 3), blk, 0, stream>>>(P);

    // logits = o @ Wout^T -> d_out f32 (overwrites all scratch regions)
    P = {o_bf, 320, Wout_bf, 320, 10112, 320, nullptr, out, 10004, 10004, nullptr,
         nullptr, nullptr, 0, 0};
    gemm_bt<3><<<dim3(50, 79), blk, 0, stream>>>(P);

    (void)in_sizes; (void)n_in; (void)out_size; (void)ws_size;
}

// Round 18
// 623.282 us; speedup vs baseline: 1.4649x; 1.0388x over previous
//
#include <hip/hip_runtime.h>

// ---------------------------------------------------------------------------
// Decoder (GRU, T=50 steps) on MI355X.
// Round 17: r12-green base (630us) + WIDE (128x256) GEMM variant for logits.
//   - gemm_bt reverted to r12 single-buffer BK=64 + reg prefetch (r16 dbuf
//     regressed +17us).
//   - NEW gemm_bt_wide: 128x256 tile, wave = 64r x 128c (acc[4][8]),
//     55KB LDS, 2 blocks/CU. Halves logits block count + A restaging,
//     doubles MFMA per barrier. Used ONLY for the logits GEMM.
//   - Scan FROZEN at r12 protocol (342us). Tail separate (r15 lesson).
// Dims: V=10004 E=300 SH=1024 H=512 G=1024 B=128 T=50.
// ---------------------------------------------------------------------------

typedef __bf16 bf16x8 __attribute__((ext_vector_type(8)));
typedef float f32x4 __attribute__((ext_vector_type(4)));
typedef unsigned long long u64;

// ---------------- merged conversion + embedding kernel ---------------------
struct CvtAll {
    const float* src[7];
    int srows[7], scols[7], sstride[7], soff[7], drows[7], dcols[7];
    __bf16* dst[7];
    int blk0[8];
    const int* x; const float* emb; __bf16* embbf;
};

__global__ void cvt_all_kernel(CvtAll p) {
    int bid = blockIdx.x;
    if (bid >= p.blk0[7]) {
        int idx = (bid - p.blk0[7]) * 256 + threadIdx.x;
        if (idx >= 6400 * 320) return;
        int m = idx / 320, c = idx - m * 320;
        int t = m >> 7, b = m & 127;
        int tok = p.x[b * 50 + t];
        float v = (c < 300) ? p.emb[(size_t)tok * 300 + c] : 0.0f;
        p.embbf[idx] = (__bf16)v;
        return;
    }
    int s = 0;
    while (s < 6 && bid >= p.blk0[s + 1]) ++s;
    int idx = (bid - p.blk0[s]) * 256 + threadIdx.x;
    int dc = p.dcols[s];
    int r = idx / dc, c = idx - r * dc;
    if (r >= p.drows[s]) return;
    float v = 0.0f;
    if (r < p.srows[s] && c < p.scols[s])
        v = p.src[s][(size_t)r * p.sstride[s] + p.soff[s] + c];
    p.dst[s][(size_t)r * dc + c] = (__bf16)v;
}

// ---------------- generic bf16 MFMA GEMM: C = A @ B^T (r12 version) --------
struct GemmParams {
    const __bf16* A; int lda;
    const __bf16* B; int ldb; int Brows;
    int K;                      // divisible by 64
    const float* bias;
    float* outF; int ldo; int Nstore;
    __bf16* outBf;
    const __bf16* res;
    const float* add2;
    int ld2; int add2lim;
};

template <int EPI>
__launch_bounds__(256, 2)
__global__ void gemm_bt(GemmParams p) {
    __shared__ __bf16 As[128][72];
    __shared__ __bf16 Bs[128][72];

    const int tid = threadIdx.x;
    const int lane = tid & 63;
    const int wid = tid >> 6;
    const int wr = wid >> 1, wc = wid & 1;
    const int m0 = blockIdx.x * 128, c0 = blockIdx.y * 128;
    const int lrow = lane & 15;
    const int kq = lane >> 4;

    int srow[4], scol[4];
#pragma unroll
    for (int i = 0; i < 4; ++i) {
        int chunk = i * 256 + tid;
        srow[i] = chunk >> 3;
        scol[i] = (chunk & 7) * 8;
    }

    f32x4 acc[4][4];
#pragma unroll
    for (int i = 0; i < 4; ++i)
#pragma unroll
        for (int j = 0; j < 4; ++j) acc[i][j] = (f32x4){0.f, 0.f, 0.f, 0.f};

    const int nkb = p.K >> 6;
    bf16x8 ra[4], rb[4];
#pragma unroll
    for (int i = 0; i < 4; ++i) {
        ra[i] = *reinterpret_cast<const bf16x8*>(
            p.A + (size_t)(m0 + srow[i]) * p.lda + scol[i]);
        bf16x8 z;
#pragma unroll
        for (int q = 0; q < 8; ++q) z[q] = (__bf16)0.0f;
        int grow = c0 + srow[i];
        rb[i] = (grow < p.Brows)
            ? *reinterpret_cast<const bf16x8*>(p.B + (size_t)grow * p.ldb + scol[i])
            : z;
    }

    for (int kb = 0; kb < nkb; ++kb) {
        __syncthreads();
#pragma unroll
        for (int i = 0; i < 4; ++i) {
            *reinterpret_cast<bf16x8*>(&As[srow[i]][scol[i]]) = ra[i];
            *reinterpret_cast<bf16x8*>(&Bs[srow[i]][scol[i]]) = rb[i];
        }
        __syncthreads();

        if (kb + 1 < nkb) {
            int ko = (kb + 1) << 6;
#pragma unroll
            for (int i = 0; i < 4; ++i) {
                ra[i] = *reinterpret_cast<const bf16x8*>(
                    p.A + (size_t)(m0 + srow[i]) * p.lda + ko + scol[i]);
                bf16x8 z;
#pragma unroll
                for (int q = 0; q < 8; ++q) z[q] = (__bf16)0.0f;
                int grow = c0 + srow[i];
                rb[i] = (grow < p.Brows)
                    ? *reinterpret_cast<const bf16x8*>(
                          p.B + (size_t)grow * p.ldb + ko + scol[i])
                    : z;
            }
        }

#pragma unroll
        for (int kk = 0; kk < 2; ++kk) {
            bf16x8 af[4], bfr[4];
#pragma unroll
            for (int m = 0; m < 4; ++m)
                af[m] = *reinterpret_cast<const bf16x8*>(
                    &As[wr * 64 + m * 16 + lrow][kk * 32 + kq * 8]);
#pragma unroll
            for (int n = 0; n < 4; ++n)
                bfr[n] = *reinterpret_cast<const bf16x8*>(
                    &Bs[wc * 64 + n * 16 + lrow][kk * 32 + kq * 8]);
#pragma unroll
            for (int m = 0; m < 4; ++m)
#pragma unroll
                for (int n = 0; n < 4; ++n)
                    acc[m][n] = __builtin_amdgcn_mfma_f32_16x16x32_bf16(
                        af[m], bfr[n], acc[m][n], 0, 0, 0);
        }
    }

#pragma unroll
    for (int m = 0; m < 4; ++m) {
#pragma unroll
        for (int n = 0; n < 4; ++n) {
#pragma unroll
            for (int i = 0; i < 4; ++i) {
                int r = m0 + wr * 64 + m * 16 + kq * 4 + i;
                int c = c0 + wc * 64 + n * 16 + lrow;
                float v = acc[m][n][i];
                if constexpr (EPI == 1) {
                    v = tanhf(v + p.bias[c]);
                    p.outBf[(size_t)r * p.ldo + c] = (__bf16)v;
                    p.outF[(size_t)c * 128 + r] = v;
                } else if constexpr (EPI == 2) {
                    int ro = (r & 127) * 50 + (r >> 7);
                    if (c < 300) {
                        v += p.bias[c] + (float)p.res[(size_t)r * 320 + c];
                        p.outBf[(size_t)ro * 320 + c] = (__bf16)v;
                    } else if (c < 320) {
                        p.outBf[(size_t)ro * 320 + c] = (__bf16)0.0f;
                    }
                } else if constexpr (EPI == 3) {
                    if (c < p.Nstore) p.outF[(size_t)r * p.ldo + c] = v;
                } else {  // EPI == 4
                    if (c < p.Brows) {
                        float v2 = v + p.bias[r];
                        if (p.add2 && r < p.add2lim)
                            v2 += p.add2[(size_t)r * 128 + (c & 127)];
                        p.outF[(size_t)(c >> 7) * p.ldo + (size_t)r * 128 + (c & 127)] = v2;
                    }
                }
            }
        }
    }
}

// ---------------- WIDE GEMM: 128x256 tile, logits only ---------------------
// Wave = 64 rows x 128 cols (acc[4][8]). LDS: A 18.4KB + B 36.9KB.
__launch_bounds__(256, 2)
__global__ void gemm_bt_wide(GemmParams p) {
    __shared__ __bf16 As[128][72];
    __shared__ __bf16 Bs[256][72];

    const int tid = threadIdx.x;
    const int lane = tid & 63;
    const int wid = tid >> 6;
    const int wr = wid >> 1, wc = wid & 1;
    const int m0 = blockIdx.x * 128, c0 = blockIdx.y * 256;
    const int lrow = lane & 15;
    const int kq = lane >> 4;

    int srA[4], scA[4], srB[8], scB[8];
#pragma unroll
    for (int i = 0; i < 4; ++i) {
        int chunk = i * 256 + tid;
        srA[i] = chunk >> 3;
        scA[i] = (chunk & 7) * 8;
    }
#pragma unroll
    for (int i = 0; i < 8; ++i) {
        int chunk = i * 256 + tid;
        srB[i] = chunk >> 3;
        scB[i] = (chunk & 7) * 8;
    }

    f32x4 acc[4][8];
#pragma unroll
    for (int i = 0; i < 4; ++i)
#pragma unroll
        for (int j = 0; j < 8; ++j) acc[i][j] = (f32x4){0.f, 0.f, 0.f, 0.f};

    const int nkb = p.K >> 6;
    bf16x8 ra[4], rb[8];
#pragma unroll
    for (int i = 0; i < 4; ++i)
        ra[i] = *reinterpret_cast<const bf16x8*>(
            p.A + (size_t)(m0 + srA[i]) * p.lda + scA[i]);
#pragma unroll
    for (int i = 0; i < 8; ++i) {
        bf16x8 z;
#pragma unroll
        for (int q = 0; q < 8; ++q) z[q] = (__bf16)0.0f;
        int grow = c0 + srB[i];
        rb[i] = (grow < p.Brows)
            ? *reinterpret_cast<const bf16x8*>(p.B + (size_t)grow * p.ldb + scB[i])
            : z;
    }

    for (int kb = 0; kb < nkb; ++kb) {
        __syncthreads();
#pragma unroll
        for (int i = 0; i < 4; ++i)
            *reinterpret_cast<bf16x8*>(&As[srA[i]][scA[i]]) = ra[i];
#pragma unroll
        for (int i = 0; i < 8; ++i)
            *reinterpret_cast<bf16x8*>(&Bs[srB[i]][scB[i]]) = rb[i];
        __syncthreads();

        if (kb + 1 < nkb) {
            int ko = (kb + 1) << 6;
#pragma unroll
            for (int i = 0; i < 4; ++i)
                ra[i] = *reinterpret_cast<const bf16x8*>(
                    p.A + (size_t)(m0 + srA[i]) * p.lda + ko + scA[i]);
#pragma unroll
            for (int i = 0; i < 8; ++i) {
                bf16x8 z;
#pragma unroll
                for (int q = 0; q < 8; ++q) z[q] = (__bf16)0.0f;
                int grow = c0 + srB[i];
                rb[i] = (grow < p.Brows)
                    ? *reinterpret_cast<const bf16x8*>(
                          p.B + (size_t)grow * p.ldb + ko + scB[i])
                    : z;
            }
        }

#pragma unroll
        for (int kk = 0; kk < 2; ++kk) {
            bf16x8 af[4], bfr[8];
#pragma unroll
            for (int m = 0; m < 4; ++m)
                af[m] = *reinterpret_cast<const bf16x8*>(
                    &As[wr * 64 + m * 16 + lrow][kk * 32 + kq * 8]);
#pragma unroll
            for (int n = 0; n < 8; ++n)
                bfr[n] = *reinterpret_cast<const bf16x8*>(
                    &Bs[wc * 128 + n * 16 + lrow][kk * 32 + kq * 8]);
#pragma unroll
            for (int m = 0; m < 4; ++m)
#pragma unroll
                for (int n = 0; n < 8; ++n)
                    acc[m][n] = __builtin_amdgcn_mfma_f32_16x16x32_bf16(
                        af[m], bfr[n], acc[m][n], 0, 0, 0);
        }
    }

    // epilogue: plain f32 store with col guard (logits)
#pragma unroll
    for (int m = 0; m < 4; ++m) {
#pragma unroll
        for (int n = 0; n < 8; ++n) {
#pragma unroll
            for (int i = 0; i < 4; ++i) {
                int r = m0 + wr * 64 + m * 16 + kq * 4 + i;
                int c = c0 + wc * 128 + n * 16 + lrow;
                if (c < p.Nstore)
                    p.outF[(size_t)r * p.ldo + c] = acc[m][n][i];
            }
        }
    }
}

// ---------------- persistent scan (r12 protocol, FROZEN) -------------------
#define SCAN_NB 64
__launch_bounds__(256, 1)
__global__ void scan_kernel(const __bf16* __restrict__ Whh_a,   // [3072][512]
                            const float* __restrict__ gxT,      // [50][3072][128]
                            const float* __restrict__ ghcT,     // [3072][128]
                            const float* __restrict__ sesT,     // [512][128] f32
                            u64* __restrict__ F,                // [51][128][256] u64
                            unsigned* __restrict__ cnt) {       // 4 ctr @ stride 32
    __shared__ char smem[131072];
    char* Ws = smem;
    char* Hs = smem + 98304;
    const int tid = threadIdx.x;
    const int lane = tid & 63;
    const int wid = tid >> 6;
    const int wr = wid >> 1, wc = wid & 1;
    const int bid = blockIdx.x;
    const int q = bid >> 4;
    const int j0 = (bid & 15) * 32;
    const int lrow = lane & 15, kq = lane >> 4;

    for (int it = 0; it < 24; ++it) {
        int c = it * 256 + tid;
        int rl = c >> 6, o16 = c & 63;
        int g = rl >> 5, jj = rl & 31;
        bf16x8 v = *reinterpret_cast<const bf16x8*>(
            Whh_a + (size_t)(g * 1024 + j0 + jj) * 512 + o16 * 8);
        *reinterpret_cast<bf16x8*>(Ws + rl * 1024 + ((o16 * 16) ^ ((rl & 7) << 4))) = v;
    }

    const int b_g = q * 32 + wc * 16 + lrow;
    const int jbase = j0 + wr * 16 + kq * 4;

    float cn[4], hprev[4], gcur[12], gpre[12];
#pragma unroll
    for (int i = 0; i < 4; ++i) {
        cn[i] = ghcT[(size_t)(2048 + jbase + i) * 128 + b_g];
        hprev[i] = sesT[(size_t)(jbase + i) * 128 + b_g];
    }
#pragma unroll
    for (int i = 0; i < 4; ++i) {
        gpre[i]     = gxT[(size_t)(jbase + i) * 128 + b_g];
        gpre[4 + i] = gxT[(size_t)(1024 + jbase + i) * 128 + b_g];
        gpre[8 + i] = gxT[(size_t)(2048 + jbase + i) * 128 + b_g];
    }

    for (int t = 0; t < 50; ++t) {
        for (int it = 0; it < 16; ++it) {
            int c = it * 256 + tid;
            int rl = c >> 7, o8 = c & 127;
            u64 v = __hip_atomic_load(
                F + ((size_t)t * 128 + q * 32 + rl) * 256 + o8,
                __ATOMIC_RELAXED, __HIP_MEMORY_SCOPE_AGENT);
            *reinterpret_cast<u64*>(Hs + rl * 1024 + ((o8 * 8) ^ ((rl & 7) << 4))) = v;
        }
#pragma unroll
        for (int i = 0; i < 12; ++i) gcur[i] = gpre[i];
        {
            int tn = (t < 49) ? t + 1 : 49;
            const float* gxt = gxT + (size_t)tn * 3072 * 128;
#pragma unroll
            for (int i = 0; i < 4; ++i) {
                gpre[i]     = gxt[(size_t)(jbase + i) * 128 + b_g];
                gpre[4 + i] = gxt[(size_t)(1024 + jbase + i) * 128 + b_g];
                gpre[8 + i] = gxt[(size_t)(2048 + jbase + i) * 128 + b_g];
            }
        }
        asm volatile("s_waitcnt lgkmcnt(0)\n\ts_barrier" ::: "memory");
        __builtin_amdgcn_sched_barrier(0);

        f32x4 acc[3];
#pragma unroll
        for (int g = 0; g < 3; ++g) acc[g] = (f32x4){0.f, 0.f, 0.f, 0.f};
        const int hrow = wc * 16 + lrow;
        const int arow0 = wr * 16 + lrow;
        for (int kb = 0; kb < 16; ++kb) {
            int ko = kb * 64 + kq * 16;
            bf16x8 hfrag = *reinterpret_cast<const bf16x8*>(
                Hs + hrow * 1024 + (ko ^ ((hrow & 7) << 4)));
#pragma unroll
            for (int g = 0; g < 3; ++g) {
                int arow = g * 32 + arow0;
                bf16x8 wfrag = *reinterpret_cast<const bf16x8*>(
                    Ws + arow * 1024 + (ko ^ ((arow & 7) << 4)));
                acc[g] = __builtin_amdgcn_mfma_f32_16x16x32_bf16(
                    wfrag, hfrag, acc[g], 0, 0, 0);
            }
        }

        union { u64 u; __bf16 h[4]; } pk;
#pragma unroll
        for (int i = 0; i < 4; ++i) {
            float r = 1.0f / (1.0f + expf(-(gcur[i] + acc[0][i])));
            float z = 1.0f / (1.0f + expf(-(gcur[4 + i] + acc[1][i])));
            float nn = tanhf(gcur[8 + i] + r * (acc[2][i] + cn[i]));
            float hn = (1.0f - z) * nn + z * hprev[i];
            hprev[i] = hn;
            pk.h[i] = (__bf16)hn;
        }
        __hip_atomic_store(
            F + ((size_t)(t + 1) * 128 + b_g) * 256 + (jbase >> 2), pk.u,
            __ATOMIC_RELAXED, __HIP_MEMORY_SCOPE_AGENT);

        if (t < 49) {
            __syncthreads();
            if (tid == 0) {
                __hip_atomic_fetch_add(cnt + q * 32, 1u,
                                       __ATOMIC_RELAXED, __HIP_MEMORY_SCOPE_AGENT);
                unsigned tgt = (unsigned)(t + 1) * 16u;
                while (__hip_atomic_load(cnt + q * 32, __ATOMIC_RELAXED,
                                         __HIP_MEMORY_SCOPE_AGENT) < tgt)
                    __builtin_amdgcn_s_sleep(1);
            }
            __syncthreads();
        }
    }
}

// ---------------- deferred non-recurrent half (j in [512,1024)) ------------
__launch_bounds__(256, 1)
__global__ void tail_kernel(const __bf16* __restrict__ Whh_a,
                            const float* __restrict__ gxT,
                            const float* __restrict__ ghcT,
                            const float* __restrict__ sesT,
                            __bf16* __restrict__ F) {
    __shared__ char smem[131072];
    char* Ws = smem;
    char* Hs = smem + 98304;
    const int tid = threadIdx.x;
    const int lane = tid & 63;
    const int wid = tid >> 6;
    const int wr = wid >> 1, wc = wid & 1;
    const int bid = blockIdx.x;
    const int tseg = bid >> 6;
    const int rem = bid & 63;
    const int q = rem >> 4;
    const int j0 = 512 + (rem & 15) * 32;
    const int lrow = lane & 15, kq = lane >> 4;

    const int t0 = (tseg < 2) ? tseg * 13 : 26 + (tseg - 2) * 12;
    const int t1 = (tseg < 2) ? t0 + 13 : t0 + 12;

    for (int it = 0; it < 24; ++it) {
        int c = it * 256 + tid;
        int rl = c >> 6, o16 = c & 63;
        int g = rl >> 5, jj = rl & 31;
        bf16x8 v = *reinterpret_cast<const bf16x8*>(
            Whh_a + (size_t)(g * 1024 + j0 + jj) * 512 + o16 * 8);
        *reinterpret_cast<bf16x8*>(Ws + rl * 1024 + ((o16 * 16) ^ ((rl & 7) << 4))) = v;
    }

    const int b_g = q * 32 + wc * 16 + lrow;
    const int jbase = j0 + wr * 16 + kq * 4;

    float cn[4], sv[4];
#pragma unroll
    for (int i = 0; i < 4; ++i) {
        cn[i] = ghcT[(size_t)(2048 + jbase + i) * 128 + b_g];
        sv[i] = sesT[(size_t)(jbase + i - 512) * 128 + b_g];
    }

    for (int tt = t0; tt < t1; ++tt) {
        for (int it = 0; it < 8; ++it) {
            int c = it * 256 + tid;
            int rl = c >> 6, o16 = c & 63;
            bf16x8 v = *reinterpret_cast<const bf16x8*>(
                F + ((size_t)tt * 128 + q * 32 + rl) * 1024 + o16 * 8);
            *reinterpret_cast<bf16x8*>(Hs + rl * 1024 + ((o16 * 16) ^ ((rl & 7) << 4))) = v;
        }
        const float* gxt = gxT + (size_t)tt * 3072 * 128;
        float g0[12];
#pragma unroll
        for (int i = 0; i < 4; ++i) {
            g0[i]     = gxt[(size_t)(jbase + i) * 128 + b_g];
            g0[4 + i] = gxt[(size_t)(1024 + jbase + i) * 128 + b_g];
            g0[8 + i] = gxt[(size_t)(2048 + jbase + i) * 128 + b_g];
        }
        __syncthreads();

        f32x4 acc[3];
#pragma unroll
        for (int g = 0; g < 3; ++g) acc[g] = (f32x4){0.f, 0.f, 0.f, 0.f};
        const int hrow = wc * 16 + lrow;
        const int arow0 = wr * 16 + lrow;
        for (int kb = 0; kb < 16; ++kb) {
            int ko = kb * 64 + kq * 16;
            bf16x8 hfrag = *reinterpret_cast<const bf16x8*>(
                Hs + hrow * 1024 + (ko ^ ((hrow & 7) << 4)));
#pragma unroll
            for (int g = 0; g < 3; ++g) {
                int arow = g * 32 + arow0;
                bf16x8 wfrag = *reinterpret_cast<const bf16x8*>(
                    Ws + arow * 1024 + (ko ^ ((arow & 7) << 4)));
                acc[g] = __builtin_amdgcn_mfma_f32_16x16x32_bf16(
                    wfrag, hfrag, acc[g], 0, 0, 0);
            }
        }

        union { u64 u; __bf16 h[4]; } pk;
#pragma unroll
        for (int i = 0; i < 4; ++i) {
            float r = 1.0f / (1.0f + expf(-(g0[i] + acc[0][i])));
            float z = 1.0f / (1.0f + expf(-(g0[4 + i] + acc[1][i])));
            float nn = tanhf(g0[8 + i] + r * (acc[2][i] + cn[i]));
            pk.h[i] = (__bf16)((1.0f - z) * nn + z * sv[i]);
        }
        *reinterpret_cast<u64*>(F + ((size_t)(tt + 1) * 128 + b_g) * 1024 + jbase) = pk.u;
        __syncthreads();
    }
}

// ---------------------------------------------------------------------------
extern "C" void kernel_launch(void* const* d_in, const int* in_sizes, int n_in,
                              void* d_out, int out_size, void* d_ws, size_t ws_size,
                              hipStream_t stream) {
    const float* ses_enc = (const float*)d_in[0];
    const int*   x       = (const int*)d_in[1];
    const float* emb     = (const float*)d_in[2];
    const float* Wih     = (const float*)d_in[3];
    const float* Whh     = (const float*)d_in[4];
    const float* bih     = (const float*)d_in[5];
    const float* bhh     = (const float*)d_in[6];
    const float* W1      = (const float*)d_in[7];
    const float* b1      = (const float*)d_in[8];
    const float* W2      = (const float*)d_in[9];
    const float* b2      = (const float*)d_in[10];
    const float* Wout    = (const float*)d_in[11];
    float* out = (float*)d_out;

    char* ws = (char*)d_ws;
    float*  sesT      = (float*)(ws + 0);
    float*  ghcT      = (float*)(ws + 262144);
    __bf16* o_bf      = (__bf16*)(ws + 1835008);
    __bf16* W1_bf     = (__bf16*)(ws + 5931008);
    __bf16* Whh_a_bf  = (__bf16*)(ws + 6979584);
    __bf16* Whh_b_bf  = (__bf16*)(ws + 10125312);
    __bf16* Wih_bf    = (__bf16*)(ws + 13271040);
    __bf16* W2_bf     = (__bf16*)(ws + 15237120);
    __bf16* Wout_bf   = (__bf16*)(ws + 15851520);
    __bf16* sesenc_bf = (__bf16*)(ws + 22323200);
    unsigned* cnt     = (unsigned*)(ws + 22585344);

    char* ob = (char*)d_out;
    float*  gxT     = (float*)ob;
    __bf16* emb_bf  = (__bf16*)(ob + 80000000);
    __bf16* F       = (__bf16*)(ob + 88000000);

    dim3 blk(256);

    CvtAll ca;
    const float* csrc[7]  = {W1, Whh, Whh, Wih, W2, Wout, ses_enc};
    int csr[7]  = {512, 3072, 3072, 3072, 300, 10004, 128};
    int csc[7]  = {1024, 512, 512, 300, 1024, 300, 1024};
    int cst[7]  = {1024, 1024, 1024, 300, 1024, 300, 1024};
    int cso[7]  = {0, 0, 512, 0, 0, 0, 0};
    __bf16* cdst[7] = {W1_bf, Whh_a_bf, Whh_b_bf, Wih_bf, W2_bf, Wout_bf, sesenc_bf};
    int cdr[7]  = {512, 3072, 3072, 3072, 300, 10112, 128};
    int cdc[7]  = {1024, 512, 512, 320, 1024, 320, 1024};
    int b0 = 0;
    for (int s = 0; s < 7; ++s) {
        ca.src[s] = csrc[s]; ca.srows[s] = csr[s]; ca.scols[s] = csc[s];
        ca.sstride[s] = cst[s]; ca.soff[s] = cso[s];
        ca.dst[s] = cdst[s]; ca.drows[s] = cdr[s]; ca.dcols[s] = cdc[s];
        ca.blk0[s] = b0;
        b0 += (cdr[s] * cdc[s] + 255) / 256;
    }
    ca.blk0[7] = b0;
    ca.x = x; ca.emb = emb; ca.embbf = emb_bf;
    int total_blocks = b0 + (6400 * 320) / 256;
    cvt_all_kernel<<<total_blocks, 256, 0, stream>>>(ca);
    hipMemsetAsync(cnt, 0, 1024, stream);

    GemmParams P;

    // ses = tanh(ses_enc @ W1^T + b1) -> F[0][b][0:512] bf16 + sesT [512][b] f32
    P = {sesenc_bf, 1024, W1_bf, 1024, 512, 1024, b1, sesT, 1024, 512, F,
         nullptr, nullptr, 0, 0};
    gemm_bt<1><<<dim3(1, 4), blk, 0, stream>>>(P);

    // ghcT[c][b] = (Whh[:,512:] @ ses^T) + bhh
    P = {Whh_b_bf, 512, F, 1024, 128, 512, bhh, ghcT, 0, 0, nullptr,
         nullptr, nullptr, 0, 0};
    gemm_bt<4><<<dim3(24, 1), blk, 0, stream>>>(P);

    // gxT[t][c][b] = (Wih @ emb^T) + bih (+ ghcT for c<2048)
    P = {Wih_bf, 320, emb_bf, 320, 6400, 320, bih, gxT, 3072 * 128, 0, nullptr,
         nullptr, ghcT, 0, 2048};
    gemm_bt<4><<<dim3(24, 50), blk, 0, stream>>>(P);

    // ---- persistent scan (recurrent half) ----
    scan_kernel<<<SCAN_NB, 256, 0, stream>>>(
        Whh_a_bf, gxT, ghcT, sesT, (u64*)F, cnt);

    // ---- deferred non-recurrent half ----
    tail_kernel<<<256, 256, 0, stream>>>(Whh_a_bf, gxT, ghcT, sesT, F);

    // o = hnew @ W2^T + b2 + emb  -> bf16, rows remapped (t,b)->(b,t)
    P = {F + 128 * 1024, 1024, W2_bf, 1024, 300, 1024, b2, nullptr, 0, 300, o_bf,
         emb_bf, nullptr, 0, 0};
    gemm_bt<2><<<dim3(50, 3), blk, 0, stream>>>(P);

    // logits = o @ Wout^T -> d_out f32  (WIDE 128x256 tiles: grid 50 x 40)
    P = {o_bf, 320, Wout_bf, 320, 10112, 320, nullptr, out, 10004, 10004, nullptr,
         nullptr, nullptr, 0, 0};
    gemm_bt_wide<<<dim3(50, 40), blk, 0, stream>>>(P);

    (void)in_sizes; (void)n_in; (void)out_size; (void)ws_size;
}